// Round 4
// baseline (389.369 us; speedup 1.0000x reference)
//
#include <hip/hip_runtime.h>
#include <math.h>

// GraphSAGE fused inference, MI355X.
// fc1 is linear (no bias/act) and agg0 = mean_n0(h1)  =>
// agg0 = concat(mean(e_n over 10), mean(e_nn over all 250)) @ W1.
//
// R4 PROBE: adds a decoy gather stream (LCG-permuted indices, weighted 1e-20)
// to double gather traffic. Purpose: (1) dur delta == real gather cost,
// (2) kernel duration rises above the harness's 153us fills so it shows up
// in rocprof top-5 with FETCH_SIZE / hbm_gbps / occupancy.
// NOT an optimization — a measurement. Revert decoys next round.

constexpr int D   = 64;
constexpr int N0  = 10;
constexpr int N1  = 25;
constexpr int NN  = N0 * N1;   // 250
constexpr int H1  = 128;
constexpr int H0  = 128;
constexpr int NT  = 256;

__device__ __forceinline__ unsigned decoy_id(int idx) {
    unsigned q = (unsigned)idx * 196314165u + 907633515u;
    return (unsigned)(((unsigned long long)q * 1000000ull) >> 32);  // [0, 1e6)
}

__global__ __launch_bounds__(NT, 4) void sage_fused(
    const int*   __restrict__ inputs,   // [B]
    const int*   __restrict__ neigh0,   // [B, 10]
    const int*   __restrict__ neigh1,   // [B, 250]
    const float* __restrict__ embed,    // [NODE_CNT+1, 64]
    const float* __restrict__ W1,       // [128, 128]
    const float* __restrict__ W0,       // [192, 128]
    const float* __restrict__ b0,       // [128]
    float*       __restrict__ out)      // [B, 128]
{
    __shared__ int   s_idx1[NN];
    __shared__ int   s_idx0[N0];
    __shared__ int   s_in;
    __shared__ float part_nn[16][D];
    __shared__ float part_en[N0][D];
    __shared__ float xbar[2 * D];
    __shared__ float x0s[D + H1];
    __shared__ float p2[2][H1];

    const int t = threadIdx.x;
    const int b = blockIdx.x;

    if (t < NN)      s_idx1[t] = neigh1[b * NN + t];
    if (t < N0)      s_idx0[t] = neigh0[b * N0 + t];
    if (t == 0)      s_in      = inputs[b];
    __syncthreads();

    // ---- phase 1: gather 261 rows, 16 lanes per 256B row (+ decoy stream) ----
    const int c4   = t & 15;
    const int s    = t >> 4;
    const int cOff = c4 * 4;

    float4 a0 = make_float4(0,0,0,0), a1 = make_float4(0,0,0,0);
    float4 a2 = make_float4(0,0,0,0), a3 = make_float4(0,0,0,0);
    float4 d0 = make_float4(0,0,0,0), d1 = make_float4(0,0,0,0);
    float4 d2 = make_float4(0,0,0,0), d3 = make_float4(0,0,0,0);
    int i = s;
    #pragma unroll 1
    for (; i + 48 < NN; i += 64) {
        const int i0 = s_idx1[i];
        const int i1 = s_idx1[i + 16];
        const int i2 = s_idx1[i + 32];
        const int i3 = s_idx1[i + 48];
        const unsigned q0 = decoy_id(i0), q1 = decoy_id(i1);
        const unsigned q2 = decoy_id(i2), q3 = decoy_id(i3);
        const float4 v0 = *(const float4*)(embed + (size_t)i0 * D + cOff);
        const float4 v1 = *(const float4*)(embed + (size_t)i1 * D + cOff);
        const float4 v2 = *(const float4*)(embed + (size_t)i2 * D + cOff);
        const float4 v3 = *(const float4*)(embed + (size_t)i3 * D + cOff);
        const float4 w0 = *(const float4*)(embed + (size_t)q0 * D + cOff);
        const float4 w1 = *(const float4*)(embed + (size_t)q1 * D + cOff);
        const float4 w2 = *(const float4*)(embed + (size_t)q2 * D + cOff);
        const float4 w3 = *(const float4*)(embed + (size_t)q3 * D + cOff);
        a0.x += v0.x; a0.y += v0.y; a0.z += v0.z; a0.w += v0.w;
        a1.x += v1.x; a1.y += v1.y; a1.z += v1.z; a1.w += v1.w;
        a2.x += v2.x; a2.y += v2.y; a2.z += v2.z; a2.w += v2.w;
        a3.x += v3.x; a3.y += v3.y; a3.z += v3.z; a3.w += v3.w;
        d0.x += w0.x; d0.y += w0.y; d0.z += w0.z; d0.w += w0.w;
        d1.x += w1.x; d1.y += w1.y; d1.z += w1.z; d1.w += w1.w;
        d2.x += w2.x; d2.y += w2.y; d2.z += w2.z; d2.w += w2.w;
        d3.x += w3.x; d3.y += w3.y; d3.z += w3.z; d3.w += w3.w;
    }
    #pragma unroll 1
    for (; i < NN; i += 16) {
        const int i0 = s_idx1[i];
        const unsigned q0 = decoy_id(i0);
        const float4 v = *(const float4*)(embed + (size_t)i0 * D + cOff);
        const float4 w = *(const float4*)(embed + (size_t)q0 * D + cOff);
        a0.x += v.x; a0.y += v.y; a0.z += v.z; a0.w += v.w;
        d0.x += w.x; d0.y += w.y; d0.z += w.z; d0.w += w.w;
    }
    // fold decoys in at 1e-20 weight: numerically invisible, not DCE-able.
    a0.x += a1.x + a2.x + a3.x + 1e-20f * (d0.x + d1.x + d2.x + d3.x);
    a0.y += a1.y + a2.y + a3.y + 1e-20f * (d0.y + d1.y + d2.y + d3.y);
    a0.z += a1.z + a2.z + a3.z + 1e-20f * (d0.z + d1.z + d2.z + d3.z);
    a0.w += a1.w + a2.w + a3.w + 1e-20f * (d0.w + d1.w + d2.w + d3.w);
    *(float4*)&part_nn[s][cOff] = a0;

    if (s < N0) {
        const float4 v = *(const float4*)(embed + (size_t)s_idx0[s] * D + cOff);
        *(float4*)&part_en[s][cOff] = v;
    }
    if (t < 16) {
        const float4 v = *(const float4*)(embed + (size_t)s_in * D + t * 4);
        *(float4*)&x0s[t * 4] = v;
    }
    __syncthreads();

    // ---- reduce partials -> xbar ----
    if (t < D) {
        float snn = 0.f;
        #pragma unroll
        for (int q = 0; q < 16; ++q) snn += part_nn[q][t];
        float sen = 0.f;
        #pragma unroll
        for (int q = 0; q < N0; ++q) sen += part_en[q][t];
        xbar[t]     = sen * (1.0f / N0);
        xbar[D + t] = snn * (1.0f / NN);
    }
    __syncthreads();

    // ---- phase 2a: agg0 = xbar @ W1 (128x128 matvec) ----
    const int j    = t & 127;
    const int half = t >> 7;
    {
        float acc = 0.f;
        const int kbase = half * 64;
        #pragma unroll 4
        for (int k4 = 0; k4 < 16; ++k4) {
            const int k = kbase + k4 * 4;
            const float4 xv = *(const float4*)&xbar[k];
            acc += xv.x * W1[(k + 0) * H1 + j];
            acc += xv.y * W1[(k + 1) * H1 + j];
            acc += xv.z * W1[(k + 2) * H1 + j];
            acc += xv.w * W1[(k + 3) * H1 + j];
        }
        p2[half][j] = acc;
    }
    __syncthreads();
    if (t < H1) x0s[D + t] = p2[0][t] + p2[1][t];
    __syncthreads();

    // ---- phase 2b: h0 = sigmoid(x0 @ W0 + b0) (192x128 matvec) ----
    {
        float acc = 0.f;
        const int kbase = half * 96;
        #pragma unroll 4
        for (int k4 = 0; k4 < 24; ++k4) {
            const int k = kbase + k4 * 4;
            const float4 xv = *(const float4*)&x0s[k];
            acc += xv.x * W0[(k + 0) * H0 + j];
            acc += xv.y * W0[(k + 1) * H0 + j];
            acc += xv.z * W0[(k + 2) * H0 + j];
            acc += xv.w * W0[(k + 3) * H0 + j];
        }
        p2[half][j] = acc;
    }
    __syncthreads();
    if (t < H0) {
        const float v = p2[0][t] + p2[1][t] + b0[t];
        out[(size_t)b * H0 + t] = 1.0f / (1.0f + __expf(-v));
    }
}

extern "C" void kernel_launch(void* const* d_in, const int* in_sizes, int n_in,
                              void* d_out, int out_size, void* d_ws, size_t ws_size,
                              hipStream_t stream) {
    const int*   inputs = (const int*)  d_in[0];
    const int*   neigh0 = (const int*)  d_in[1];
    const int*   neigh1 = (const int*)  d_in[2];
    const float* embed  = (const float*)d_in[3];
    const float* W1     = (const float*)d_in[4];
    const float* W0     = (const float*)d_in[5];
    const float* b0     = (const float*)d_in[6];
    float*       out    = (float*)d_out;

    const int B = in_sizes[0];   // 4096
    sage_fused<<<dim3(B), dim3(NT), 0, stream>>>(
        inputs, neigh0, neigh1, embed, W1, W0, b0, out);
}

// Round 5
// 362.816 us; speedup vs baseline: 1.0732x; 1.0732x over previous
//
#include <hip/hip_runtime.h>
#include <math.h>

// GraphSAGE fused inference, MI355X.
// fc1 is linear (no bias/act) and agg0 = mean_n0(h1)  =>
// agg0 = concat(mean(e_n over 10), mean(e_nn over all 250)) @ W1.
//
// R5: decoy probe (R4) reverted. Probe result: +274 MB random gather cost
// only +28 us => gathers are Infinity-Cache-served (~9.8 TB/s marginal);
// gather phase ~30 us total. Bench dur (~360 us) is dominated by fixed
// harness restore/poison traffic (1 GB fill = 153 us @ 82% HBM + 256 MB
// table restore). Kernel variants BPB=2 / BPB=1 / deep-ILP all within 1%.

constexpr int D   = 64;
constexpr int N0  = 10;
constexpr int N1  = 25;
constexpr int NN  = N0 * N1;   // 250
constexpr int H1  = 128;
constexpr int H0  = 128;
constexpr int NT  = 256;

__global__ __launch_bounds__(NT, 4) void sage_fused(
    const int*   __restrict__ inputs,   // [B]
    const int*   __restrict__ neigh0,   // [B, 10]
    const int*   __restrict__ neigh1,   // [B, 250]
    const float* __restrict__ embed,    // [NODE_CNT+1, 64]
    const float* __restrict__ W1,       // [128, 128]
    const float* __restrict__ W0,       // [192, 128]
    const float* __restrict__ b0,       // [128]
    float*       __restrict__ out)      // [B, 128]
{
    __shared__ int   s_idx1[NN];        // 250 ints
    __shared__ int   s_idx0[N0];
    __shared__ int   s_in;
    __shared__ float part_nn[16][D];    // 4 KB
    __shared__ float part_en[N0][D];    // 2.5 KB
    __shared__ float xbar[2 * D];       // [mean e_n | mean e_nn]
    __shared__ float x0s[D + H1];       // [e_v | agg0]
    __shared__ float p2[2][H1];

    const int t = threadIdx.x;
    const int b = blockIdx.x;

    // ---- stage indices ----
    if (t < NN)      s_idx1[t] = neigh1[b * NN + t];
    if (t < N0)      s_idx0[t] = neigh0[b * N0 + t];
    if (t == 0)      s_in      = inputs[b];
    __syncthreads();

    // ---- phase 1: gather 261 rows, 16 lanes per 256B row ----
    const int c4   = t & 15;        // 16B chunk within row
    const int s    = t >> 4;        // slot 0..15
    const int cOff = c4 * 4;

    float4 a0 = make_float4(0,0,0,0), a1 = make_float4(0,0,0,0);
    float4 a2 = make_float4(0,0,0,0), a3 = make_float4(0,0,0,0);
    int i = s;
    #pragma unroll 1
    for (; i + 48 < NN; i += 64) {   // 4 independent loads in flight
        const int i0 = s_idx1[i];
        const int i1 = s_idx1[i + 16];
        const int i2 = s_idx1[i + 32];
        const int i3 = s_idx1[i + 48];
        const float4 v0 = *(const float4*)(embed + (size_t)i0 * D + cOff);
        const float4 v1 = *(const float4*)(embed + (size_t)i1 * D + cOff);
        const float4 v2 = *(const float4*)(embed + (size_t)i2 * D + cOff);
        const float4 v3 = *(const float4*)(embed + (size_t)i3 * D + cOff);
        a0.x += v0.x; a0.y += v0.y; a0.z += v0.z; a0.w += v0.w;
        a1.x += v1.x; a1.y += v1.y; a1.z += v1.z; a1.w += v1.w;
        a2.x += v2.x; a2.y += v2.y; a2.z += v2.z; a2.w += v2.w;
        a3.x += v3.x; a3.y += v3.y; a3.z += v3.z; a3.w += v3.w;
    }
    #pragma unroll 1
    for (; i < NN; i += 16) {
        const float4 v = *(const float4*)(embed + (size_t)s_idx1[i] * D + cOff);
        a0.x += v.x; a0.y += v.y; a0.z += v.z; a0.w += v.w;
    }
    a0.x += a1.x + a2.x + a3.x;  a0.y += a1.y + a2.y + a3.y;
    a0.z += a1.z + a2.z + a3.z;  a0.w += a1.w + a2.w + a3.w;
    *(float4*)&part_nn[s][cOff] = a0;

    if (s < N0) {   // one e_n row per slot
        const float4 v = *(const float4*)(embed + (size_t)s_idx0[s] * D + cOff);
        *(float4*)&part_en[s][cOff] = v;
    }
    if (t < 16) {   // e_v row
        const float4 v = *(const float4*)(embed + (size_t)s_in * D + t * 4);
        *(float4*)&x0s[t * 4] = v;
    }
    __syncthreads();

    // ---- reduce partials -> xbar ----
    if (t < D) {
        float snn = 0.f;
        #pragma unroll
        for (int q = 0; q < 16; ++q) snn += part_nn[q][t];
        float sen = 0.f;
        #pragma unroll
        for (int q = 0; q < N0; ++q) sen += part_en[q][t];
        xbar[t]     = sen * (1.0f / N0);
        xbar[D + t] = snn * (1.0f / NN);
    }
    __syncthreads();

    // ---- phase 2a: agg0 = xbar @ W1 (128x128 matvec) ----
    const int j    = t & 127;
    const int half = t >> 7;
    {
        float acc = 0.f;
        const int kbase = half * 64;
        #pragma unroll 4
        for (int k4 = 0; k4 < 16; ++k4) {
            const int k = kbase + k4 * 4;
            const float4 xv = *(const float4*)&xbar[k];
            acc += xv.x * W1[(k + 0) * H1 + j];
            acc += xv.y * W1[(k + 1) * H1 + j];
            acc += xv.z * W1[(k + 2) * H1 + j];
            acc += xv.w * W1[(k + 3) * H1 + j];
        }
        p2[half][j] = acc;
    }
    __syncthreads();
    if (t < H1) x0s[D + t] = p2[0][t] + p2[1][t];
    __syncthreads();

    // ---- phase 2b: h0 = sigmoid(x0 @ W0 + b0) (192x128 matvec) ----
    {
        float acc = 0.f;
        const int kbase = half * 96;
        #pragma unroll 4
        for (int k4 = 0; k4 < 24; ++k4) {
            const int k = kbase + k4 * 4;
            const float4 xv = *(const float4*)&x0s[k];
            acc += xv.x * W0[(k + 0) * H0 + j];
            acc += xv.y * W0[(k + 1) * H0 + j];
            acc += xv.z * W0[(k + 2) * H0 + j];
            acc += xv.w * W0[(k + 3) * H0 + j];
        }
        p2[half][j] = acc;
    }
    __syncthreads();
    if (t < H0) {
        const float v = p2[0][t] + p2[1][t] + b0[t];
        out[(size_t)b * H0 + t] = 1.0f / (1.0f + __expf(-v));
    }
}

extern "C" void kernel_launch(void* const* d_in, const int* in_sizes, int n_in,
                              void* d_out, int out_size, void* d_ws, size_t ws_size,
                              hipStream_t stream) {
    const int*   inputs = (const int*)  d_in[0];
    const int*   neigh0 = (const int*)  d_in[1];
    const int*   neigh1 = (const int*)  d_in[2];
    const float* embed  = (const float*)d_in[3];
    const float* W1     = (const float*)d_in[4];
    const float* W0     = (const float*)d_in[5];
    const float* b0     = (const float*)d_in[6];
    float*       out    = (float*)d_out;

    const int B = in_sizes[0];   // 4096
    sage_fused<<<dim3(B), dim3(NT), 0, stream>>>(
        inputs, neigh0, neigh1, embed, W1, W0, b0, out);
}